// Round 2
// baseline (383.632 us; speedup 1.0000x reference)
//
#include <hip/hip_runtime.h>

#define NFACE 400000
#define NVERT 200000
#define CIN 64
#define COUT 128
#define KF 27
#define BN_EPS 1e-5f

// ---------------- Kernel 1: per-face spatial mix + scatter to vertices ----
__global__ __launch_bounds__(256) void face_scatter_k(
    const float* __restrict__ inputs,   // [NF,64]
    const float* __restrict__ filt,     // [NF,27]
    const int*   __restrict__ face,     // [NF,3]
    const float* __restrict__ sw,       // [27,64]
    float* __restrict__ agg)            // [NV,64]
{
    __shared__ float swl[KF * 64];
    for (int i = threadIdx.x; i < KF * 64; i += 256) swl[i] = sw[i];
    __syncthreads();

    const int lane = threadIdx.x & 63;
    const int wid  = threadIdx.x >> 6;          // 0..3
    int f = blockIdx.x * 16 + wid;              // 16 faces per block, 4 per wave
#pragma unroll
    for (int it = 0; it < 4; ++it, f += 4) {
        float fcv = 0.f;
        if (lane < KF) fcv = filt[f * KF + lane];
        float w = 0.f;
#pragma unroll
        for (int k = 0; k < KF; ++k)
            w += __shfl(fcv, k) * swl[k * 64 + lane];
        float contrib = inputs[f * 64 + lane] * w;
        int v0 = face[f * 3 + 0];
        int v1 = face[f * 3 + 1];
        int v2 = face[f * 3 + 2];
        atomicAdd(&agg[v0 * 64 + lane], contrib);
        atomicAdd(&agg[v1 * 64 + lane], contrib);
        atomicAdd(&agg[v2 * 64 + lane], contrib);
    }
}

// ---------------- Kernel 2: gather + pointwise conv + bias + ReLU + BN stats
#define BV 32   // vertices per block
__global__ __launch_bounds__(256) void pconv_k(
    const float* __restrict__ agg,       // [NV,64]
    const int* __restrict__ nf_count,    // [NV]
    const int* __restrict__ vt_map,      // [NV] (JAX x64-disabled -> int32)
    const float* __restrict__ dw,        // [64,128]
    const float* __restrict__ bias,      // [128]
    float* __restrict__ out,             // [NV,128]
    float* __restrict__ stats)           // [8][256]: [stripe][c]=sum, [stripe][128+c]=sumsq
{
    __shared__ float W[64 * 128];   // 32 KB
    __shared__ float A[BV][64];     // 8 KB
    for (int i = threadIdx.x; i < 64 * 128; i += 256) W[i] = dw[i];

    const int vbase = blockIdx.x * BV;
    // stage BV agg rows (already divided by denom, vt_map applied)
    for (int i = threadIdx.x; i < BV * 64; i += 256) {
        int vv = vbase + (i >> 6);
        int src = vt_map[vv];
        float denom = (float)max(nf_count[src], 1);
        A[i >> 6][i & 63] = agg[(size_t)src * 64 + (i & 63)] / denom;
    }
    __syncthreads();

    const int c    = threadIdx.x & 127;
    const int half = threadIdx.x >> 7;  // 0/1
    float s = 0.f, s2 = 0.f;
    for (int vi = half * (BV / 2); vi < (half + 1) * (BV / 2); ++vi) {
        const float4* A4 = reinterpret_cast<const float4*>(&A[vi][0]);
        float acc = bias[c];
#pragma unroll
        for (int k4 = 0; k4 < 16; ++k4) {
            float4 a = A4[k4];
            acc += a.x * W[(k4 * 4 + 0) * 128 + c];
            acc += a.y * W[(k4 * 4 + 1) * 128 + c];
            acc += a.z * W[(k4 * 4 + 2) * 128 + c];
            acc += a.w * W[(k4 * 4 + 3) * 128 + c];
        }
        acc = fmaxf(acc, 0.f);
        out[(size_t)(vbase + vi) * 128 + c] = acc;
        s  += acc;
        s2 += acc * acc;
    }
    // striped stats atomics to cut same-address contention 8x
    float* st = stats + (blockIdx.x & 7) * 256;
    atomicAdd(&st[c], s);
    atomicAdd(&st[128 + c], s2);
}

// ---------------- Kernel 3: BatchNorm finalize (in place on d_out) --------
__global__ __launch_bounds__(256) void bn_k(
    float* __restrict__ out,
    const float* __restrict__ stats,
    const float* __restrict__ gamma,
    const float* __restrict__ beta)
{
    __shared__ float sc[128], sh[128];
    if (threadIdx.x < 128) {
        int c = threadIdx.x;
        float s = 0.f, s2 = 0.f;
#pragma unroll
        for (int r = 0; r < 8; ++r) {
            s  += stats[r * 256 + c];
            s2 += stats[r * 256 + 128 + c];
        }
        float mean = s / (float)NVERT;
        float var  = s2 / (float)NVERT - mean * mean;
        float inv  = rsqrtf(var + BN_EPS) * gamma[c];
        sc[c] = inv;
        sh[c] = beta[c] - mean * inv;
    }
    __syncthreads();

    float4* o4 = reinterpret_cast<float4*>(out);
    size_t total4 = (size_t)NVERT * COUT / 4;
    for (size_t i = (size_t)blockIdx.x * 256 + threadIdx.x; i < total4;
         i += (size_t)gridDim.x * 256) {
        int c0 = (int)((i * 4) & 127);
        float4 v = o4[i];
        v.x = v.x * sc[c0 + 0] + sh[c0 + 0];
        v.y = v.y * sc[c0 + 1] + sh[c0 + 1];
        v.z = v.z * sc[c0 + 2] + sh[c0 + 2];
        v.w = v.w * sc[c0 + 3] + sh[c0 + 3];
        o4[i] = v;
    }
}

extern "C" void kernel_launch(void* const* d_in, const int* in_sizes, int n_in,
                              void* d_out, int out_size, void* d_ws, size_t ws_size,
                              hipStream_t stream) {
    const float* inputs   = (const float*)d_in[0];
    const float* filt     = (const float*)d_in[1];
    const int*   face     = (const int*)d_in[2];
    const int*   nf_count = (const int*)d_in[3];
    const int*   vt_map   = (const int*)d_in[4];
    const float* sw       = (const float*)d_in[5];
    const float* dw       = (const float*)d_in[6];
    const float* bias     = (const float*)d_in[7];
    const float* gamma    = (const float*)d_in[8];
    const float* beta     = (const float*)d_in[9];
    float* out = (float*)d_out;

    float* stats = (float*)d_ws;                       // 8*256 floats = 8 KB
    float* agg   = (float*)((char*)d_ws + 8192);       // [NV,64] f32 = 51.2 MB

    hipMemsetAsync(d_ws, 0, 8192 + (size_t)NVERT * CIN * sizeof(float), stream);

    face_scatter_k<<<NFACE / 16, 256, 0, stream>>>(inputs, filt, face, sw, agg);
    pconv_k<<<NVERT / BV, 256, 0, stream>>>(agg, nf_count, vt_map, dw, bias, out, stats);
    bn_k<<<2048, 256, 0, stream>>>(out, stats, gamma, beta);
}